// Round 1
// baseline (1851.464 us; speedup 1.0000x reference)
//
#include <hip/hip_runtime.h>

typedef unsigned short u16;
typedef unsigned int u32;
typedef __bf16 bf16x8 __attribute__((ext_vector_type(8)));
typedef u16 u16x8 __attribute__((ext_vector_type(8)));
typedef float f32x4 __attribute__((ext_vector_type(4)));

#define KOFF 27
#define NWAVES 8192
#define EPSV 1e-5f

__device__ __forceinline__ u16 f2bf(float f) {
  u32 u = __builtin_bit_cast(u32, f);
  u = (u + 0x7FFFu + ((u >> 16) & 1u)) >> 16;
  return (u16)u;
}
__device__ __forceinline__ float bf2f(u16 h) {
  return __builtin_bit_cast(float, (u32)h << 16);
}

// ---- x (f32) -> bf16, vectorized ----
__global__ void prep_x(const float* __restrict__ x, u16* __restrict__ xg, int n8) {
  int stride = gridDim.x * blockDim.x;
  for (int i = blockIdx.x * blockDim.x + threadIdx.x; i < n8; i += stride) {
    const f32x4* p = reinterpret_cast<const f32x4*>(x) + i * 2;
    f32x4 v0 = p[0], v1 = p[1];
    u16x8 o;
    o[0] = f2bf(v0[0]); o[1] = f2bf(v0[1]); o[2] = f2bf(v0[2]); o[3] = f2bf(v0[3]);
    o[4] = f2bf(v1[0]); o[5] = f2bf(v1[1]); o[6] = f2bf(v1[2]); o[7] = f2bf(v1[3]);
    reinterpret_cast<u16x8*>(xg)[i] = o;
  }
}

// ---- W1,W2 (f32 [K][Cin][Cout]) -> bf16 B-fragments in MFMA lane order ----
// unit index u = k*512 + c*256 + nt*64 + lane ; element j of lane = B[c*32+(lane>>4)*8+j][nt*16+(lane&15)]
__global__ void prep_w(const float* __restrict__ W1, const float* __restrict__ W2,
                       u16* __restrict__ wf) {
  int tid = blockIdx.x * blockDim.x + threadIdx.x;
  if (tid >= 27648) return;
  int conv = tid / 13824;
  int slot = tid - conv * 13824;
  const float* src = conv ? W2 : W1;
  int k = slot >> 9;
  int c = (slot >> 8) & 1;
  int nt = (slot >> 6) & 3;
  int lane = slot & 63;
  int col = nt * 16 + (lane & 15);
  int kk0 = c * 32 + (lane >> 4) * 8;
  int base = k * 4096 + kk0 * 64 + col;
  u16x8 o;
#pragma unroll
  for (int j = 0; j < 8; j++) o[j] = f2bf(src[base + j * 64]);
  reinterpret_cast<u16x8*>(wf)[tid] = o;
}

// ---- sparse conv: out[n] = sum_k mask[n,k] * xg[nbr[n,k]] @ W[k], + BN partial stats ----
__global__ __launch_bounds__(256) void sconv(
    const u16* __restrict__ xg, const int* __restrict__ nbr,
    const int* __restrict__ msk, const u16* __restrict__ wf,
    u16* __restrict__ hout, float* __restrict__ psum, float* __restrict__ psq,
    int ntiles) {
  const int lane = threadIdx.x & 63;
  const int r = lane & 15;        // A row within tile / C col within 16-group
  const int kg = lane >> 4;       // k-group
  const int waveId = blockIdx.x * (blockDim.x >> 6) + (threadIdx.x >> 6);
  bf16x8 zz;
#pragma unroll
  for (int j = 0; j < 8; j++) zz[j] = (__bf16)0.0f;
  float ssum[4] = {0.f, 0.f, 0.f, 0.f};
  float ssq[4] = {0.f, 0.f, 0.f, 0.f};
  const bf16x8* wfv = reinterpret_cast<const bf16x8*>(wf);

  for (int t = waveId; t < ntiles; t += NWAVES) {
    const int n0 = t * 16;
    const int ibase = (n0 + r) * KOFF;
    f32x4 acc[4];
#pragma unroll
    for (int nt = 0; nt < 4; nt++) {
      acc[nt][0] = 0.f; acc[nt][1] = 0.f; acc[nt][2] = 0.f; acc[nt][3] = 0.f;
    }
    for (int k = 0; k < KOFF; k++) {
      int idx = nbr[ibase + k];
      int m = msk[ibase + k];
      bf16x8 a0 = zz, a1 = zz;
      if (m) {
        const bf16x8* ap = reinterpret_cast<const bf16x8*>(xg + idx * 64 + kg * 8);
        a0 = ap[0];   // channels [kg*8, kg*8+8)
        a1 = ap[4];   // channels [32+kg*8, 32+kg*8+8)
      }
      const bf16x8* bp = wfv + (k << 9) + lane;
#pragma unroll
      for (int nt = 0; nt < 4; nt++) {
        acc[nt] = __builtin_amdgcn_mfma_f32_16x16x32_bf16(a0, bp[nt * 64], acc[nt], 0, 0, 0);
        acc[nt] = __builtin_amdgcn_mfma_f32_16x16x32_bf16(a1, bp[256 + nt * 64], acc[nt], 0, 0, 0);
      }
    }
    // C/D layout: col = lane&15 (+16*nt), row = kg*4 + reg
#pragma unroll
    for (int nt = 0; nt < 4; nt++) {
      const int col = nt * 16 + r;
      float rs = 0.f, rq = 0.f;
#pragma unroll
      for (int reg = 0; reg < 4; reg++) {
        float v = acc[nt][reg];
        rs += v;
        rq += v * v;
        hout[(n0 + kg * 4 + reg) * 64 + col] = f2bf(v);
      }
      ssum[nt] += rs;
      ssq[nt] += rq;
    }
  }
  // reduce the 4 row-groups (lanes with same lane&15) -> per-channel wave partials
#pragma unroll
  for (int nt = 0; nt < 4; nt++) {
    ssum[nt] += __shfl_xor(ssum[nt], 16, 64);
    ssum[nt] += __shfl_xor(ssum[nt], 32, 64);
    ssq[nt] += __shfl_xor(ssq[nt], 16, 64);
    ssq[nt] += __shfl_xor(ssq[nt], 32, 64);
  }
  if (lane < 16) {
#pragma unroll
    for (int nt = 0; nt < 4; nt++) {
      psum[waveId * 64 + nt * 16 + lane] = ssum[nt];
      psq[waveId * 64 + nt * 16 + lane] = ssq[nt];
    }
  }
}

// ---- finalize BN: one block per channel ----
__global__ void bn_finalize(const float* __restrict__ psum, const float* __restrict__ psq,
                            const float* __restrict__ g, const float* __restrict__ b,
                            float* __restrict__ scale, float* __restrict__ shift, float invN) {
  int c = blockIdx.x;
  float s = 0.f, q = 0.f;
  for (int i = threadIdx.x; i < NWAVES; i += blockDim.x) {
    s += psum[i * 64 + c];
    q += psq[i * 64 + c];
  }
#pragma unroll
  for (int off = 32; off >= 1; off >>= 1) {
    s += __shfl_down(s, off, 64);
    q += __shfl_down(q, off, 64);
  }
  __shared__ float ls[4], lq[4];
  int wid = threadIdx.x >> 6;
  int lane = threadIdx.x & 63;
  if (lane == 0) { ls[wid] = s; lq[wid] = q; }
  __syncthreads();
  if (threadIdx.x == 0) {
    s = ls[0] + ls[1] + ls[2] + ls[3];
    q = lq[0] + lq[1] + lq[2] + lq[3];
    float mean = s * invN;
    float var = q * invN - mean * mean;
    float rstd = rsqrtf(var + EPSV);
    float sc = rstd * g[c];
    scale[c] = sc;
    shift[c] = b[c] - mean * sc;
  }
}

// ---- y = relu(h*scale + shift) (bf16 -> bf16) ----
__global__ void bn_relu_apply(const u16* __restrict__ h, const float* __restrict__ scale,
                              const float* __restrict__ shift, u16* __restrict__ y, int n8) {
  int i0 = blockIdx.x * blockDim.x + threadIdx.x;
  int c0 = (i0 * 8) & 63;
  float sc[8], sh[8];
#pragma unroll
  for (int j = 0; j < 8; j++) { sc[j] = scale[c0 + j]; sh[j] = shift[c0 + j]; }
  int stride = gridDim.x * blockDim.x;  // stride*8 is a multiple of 64 -> c0 invariant
  for (int i = i0; i < n8; i += stride) {
    u16x8 hv = reinterpret_cast<const u16x8*>(h)[i];
    u16x8 o;
#pragma unroll
    for (int j = 0; j < 8; j++) {
      float f = bf2f(hv[j]) * sc[j] + sh[j];
      o[j] = f2bf(fmaxf(f, 0.f));
    }
    reinterpret_cast<u16x8*>(y)[i] = o;
  }
}

// ---- out = relu(h*scale + shift + x) (f32 out) ----
__global__ void bn_add_relu(const u16* __restrict__ h, const float* __restrict__ scale,
                            const float* __restrict__ shift, const float* __restrict__ x,
                            float* __restrict__ out, int n8) {
  int i0 = blockIdx.x * blockDim.x + threadIdx.x;
  int c0 = (i0 * 8) & 63;
  float sc[8], sh[8];
#pragma unroll
  for (int j = 0; j < 8; j++) { sc[j] = scale[c0 + j]; sh[j] = shift[c0 + j]; }
  int stride = gridDim.x * blockDim.x;
  for (int i = i0; i < n8; i += stride) {
    u16x8 hv = reinterpret_cast<const u16x8*>(h)[i];
    const f32x4* xp = reinterpret_cast<const f32x4*>(x) + i * 2;
    f32x4 x0 = xp[0], x1 = xp[1];
    f32x4 o0, o1;
#pragma unroll
    for (int j = 0; j < 4; j++) {
      o0[j] = fmaxf(bf2f(hv[j]) * sc[j] + sh[j] + x0[j], 0.f);
      o1[j] = fmaxf(bf2f(hv[j + 4]) * sc[j + 4] + sh[j + 4] + x1[j], 0.f);
    }
    f32x4* op = reinterpret_cast<f32x4*>(out) + i * 2;
    op[0] = o0;
    op[1] = o1;
  }
}

extern "C" void kernel_launch(void* const* d_in, const int* in_sizes, int n_in,
                              void* d_out, int out_size, void* d_ws, size_t ws_size,
                              hipStream_t stream) {
  const float* x = (const float*)d_in[0];
  const int* nbr = (const int*)d_in[1];
  const int* msk = (const int*)d_in[2];
  const float* W1 = (const float*)d_in[3];
  const float* g1 = (const float*)d_in[4];
  const float* b1 = (const float*)d_in[5];
  const float* W2 = (const float*)d_in[6];
  const float* g2 = (const float*)d_in[7];
  const float* b2 = (const float*)d_in[8];
  float* out = (float*)d_out;

  const int N = in_sizes[0] / 64;   // 800000
  const int ntiles = N / 16;        // 50000
  const int n8 = N * 8;             // N*64/8
  const size_t NC2 = (size_t)N * 64 * 2;  // bytes of one bf16 feature map

  char* ws = (char*)d_ws;
  u16* bufA = (u16*)ws;                       // xg, then y1
  u16* bufB = (u16*)(ws + NC2);               // h1, then h2
  u16* wf = (u16*)(ws + 2 * NC2);             // 2 * 221184 B of fragments
  float* psum = (float*)(ws + 2 * NC2 + 512 * 1024);
  float* psq = psum + NWAVES * 64;
  float* sc = psq + NWAVES * 64;              // scale1|shift1|scale2|shift2 (4*64 f32)

  float invN = 1.0f / (float)N;

  prep_x<<<2048, 256, 0, stream>>>(x, bufA, n8);
  prep_w<<<108, 256, 0, stream>>>(W1, W2, wf);
  sconv<<<2048, 256, 0, stream>>>(bufA, nbr, msk, wf, bufB, psum, psq, ntiles);
  bn_finalize<<<64, 256, 0, stream>>>(psum, psq, g1, b1, sc, sc + 64, invN);
  bn_relu_apply<<<2048, 256, 0, stream>>>(bufB, sc, sc + 64, bufA, n8);
  sconv<<<2048, 256, 0, stream>>>(bufA, nbr, msk, wf + 110592, bufB, psum, psq, ntiles);
  bn_finalize<<<64, 256, 0, stream>>>(psum, psq, g2, b2, sc + 128, sc + 192, invN);
  bn_add_relu<<<2048, 256, 0, stream>>>(bufB, sc + 128, sc + 192, x, out, n8);
}